// Round 2
// baseline (67.222 us; speedup 1.0000x reference)
//
#include <hip/hip_runtime.h>

// Problem constants (fixed by the reference).
constexpr int Bn = 8192;
constexpr int Kn = 256;
constexpr int Dn = 128;

// Workspace layout (floats): zz[B][D][2] | ab[K][D][2] | c[K]
constexpr size_t ZZ_F = (size_t)Bn * Dn * 2;   // 2,097,152
constexpr size_t AB_F = (size_t)Kn * Dn * 2;   //    65,536
constexpr size_t C_F  = (size_t)Kn;            //       256
constexpr size_t NEED_BYTES = (ZZ_F + AB_F + C_F) * sizeof(float);

// ---------------------------------------------------------------------------
// Pre-pass: zz = {z, z^2} interleaved; ab = {a, b} interleaved with
// a = exp(-logvar) (=1/var), b = -2*mu*a; c[k] = sum_d mu^2 * a.
// dist[b,k] = sum_d (z^2*a + z*b) + c[k]  ==  sum_d (z-mu)^2 / var.
// ---------------------------------------------------------------------------
__global__ __launch_bounds__(256)
void prep_kernel(const float* __restrict__ z, const float* __restrict__ cent,
                 const float* __restrict__ logvar, float* __restrict__ ws)
{
    const int tid = threadIdx.x;
    const int blk = blockIdx.x;
    float* zz = ws;
    float* ab = ws + ZZ_F;
    float* cc = ws + ZZ_F + AB_F;

    if (blk < 1024) {
        // zz fill: 1024 blocks * 256 thr * 4 f32 = 1,048,576 elements
        const int i4 = (blk * 256 + tid) * 4;
        const float4 v = *reinterpret_cast<const float4*>(z + i4);
        float4 w0 = make_float4(v.x, v.x * v.x, v.y, v.y * v.y);
        float4 w1 = make_float4(v.z, v.z * v.z, v.w, v.w * v.w);
        *reinterpret_cast<float4*>(zz + (size_t)i4 * 2)     = w0;
        *reinterpret_cast<float4*>(zz + (size_t)i4 * 2 + 4) = w1;
    } else {
        // ab + c: 32 blocks, 8 k per block; 32 lanes (x4 d) per k
        const int k0 = (blk - 1024) * 8;
        const int kl = tid >> 5;     // 0..7
        const int dq = tid & 31;     // d = dq*4 .. dq*4+3
        const int k  = k0 + kl;
        const float4 cv = *reinterpret_cast<const float4*>(cent   + k * Dn + dq * 4);
        const float4 lv = *reinterpret_cast<const float4*>(logvar + k * Dn + dq * 4);
        const float a0 = expf(-lv.x), a1 = expf(-lv.y), a2 = expf(-lv.z), a3 = expf(-lv.w);
        const float t0 = cv.x * a0, t1 = cv.y * a1, t2 = cv.z * a2, t3 = cv.w * a3;
        *reinterpret_cast<float4*>(ab + ((size_t)k * Dn + dq * 4) * 2)     =
            make_float4(a0, -2.0f * t0, a1, -2.0f * t1);
        *reinterpret_cast<float4*>(ab + ((size_t)k * Dn + dq * 4) * 2 + 4) =
            make_float4(a2, -2.0f * t2, a3, -2.0f * t3);
        float cp = t0 * cv.x + t1 * cv.y + t2 * cv.z + t3 * cv.w;
        #pragma unroll
        for (int m = 16; m >= 1; m >>= 1) cp += __shfl_xor(cp, m);
        if (dq == 0) cc[k] = cp;
    }
}

// ---------------------------------------------------------------------------
// Main: 512 blocks x 512 threads. Thread = (k = tid&255, half = tid>>8),
// owns 8 rows. Inner loop: pure FMA, ab per-lane gather (L1-resident),
// zz wave-uniform loads (scalar path). No LDS in hot loop.
// ---------------------------------------------------------------------------
__global__ __launch_bounds__(512, 4)
void gmm_main(const float* __restrict__ ws, float* __restrict__ out)
{
    const int tid  = threadIdx.x;
    const int k    = tid & 255;
    const int half = tid >> 8;      // 0/1 (wave-uniform)
    const int wv   = tid >> 6;      // wave id 0..7
    const int b0   = blockIdx.x * 16;

    const float* zz = ws;
    const float* ab = ws + ZZ_F;
    const float* cc = ws + ZZ_F + AB_F;

    // force the wave-uniform row base into an SGPR so zz loads scalarize
    const int half_u = __builtin_amdgcn_readfirstlane(half);
    const size_t zbase = (size_t)(b0 + half_u * 8) * (Dn * 2);
    const float* abk = ab + (size_t)k * (Dn * 2);

    float acc[8];
    #pragma unroll
    for (int r = 0; r < 8; ++r) acc[r] = 0.0f;

    #pragma unroll 2
    for (int dg = 0; dg < 16; ++dg) {         // 8 d's per iteration
        const int d0 = dg * 8;
        float4 A[4];
        #pragma unroll
        for (int j = 0; j < 4; ++j)
            A[j] = *reinterpret_cast<const float4*>(abk + d0 * 2 + j * 4);

        #pragma unroll
        for (int r = 0; r < 8; ++r) {
            const float* zp = zz + zbase + (size_t)r * (Dn * 2) + d0 * 2;
            const float4 q0 = *reinterpret_cast<const float4*>(zp);
            const float4 q1 = *reinterpret_cast<const float4*>(zp + 4);
            const float4 q2 = *reinterpret_cast<const float4*>(zp + 8);
            const float4 q3 = *reinterpret_cast<const float4*>(zp + 12);
            float a = acc[r];
            a = fmaf(q0.y, A[0].x, a); a = fmaf(q0.x, A[0].y, a);
            a = fmaf(q0.w, A[0].z, a); a = fmaf(q0.z, A[0].w, a);
            a = fmaf(q1.y, A[1].x, a); a = fmaf(q1.x, A[1].y, a);
            a = fmaf(q1.w, A[1].z, a); a = fmaf(q1.z, A[1].w, a);
            a = fmaf(q2.y, A[2].x, a); a = fmaf(q2.x, A[2].y, a);
            a = fmaf(q2.w, A[2].z, a); a = fmaf(q2.z, A[2].w, a);
            a = fmaf(q3.y, A[3].x, a); a = fmaf(q3.x, A[3].y, a);
            a = fmaf(q3.w, A[3].z, a); a = fmaf(q3.z, A[3].w, a);
            acc[r] = a;
        }
    }

    // ---- softmax over k (wave reduce + tiny LDS cross-wave combine) ----
    __shared__ float red1[8][8];   // [wave][row] partial min
    __shared__ float red2[8][8];   // [wave][row] partial sum

    const float ck = cc[k];
    #pragma unroll
    for (int r = 0; r < 8; ++r) {
        acc[r] += ck;              // acc = dist
        float t = acc[r];
        #pragma unroll
        for (int msk = 32; msk >= 1; msk >>= 1) t = fminf(t, __shfl_xor(t, msk));
        if ((tid & 63) == 0) red1[wv][r] = t;
    }
    __syncthreads();

    #pragma unroll
    for (int r = 0; r < 8; ++r) {
        const float gm = fminf(fminf(red1[half * 4 + 0][r], red1[half * 4 + 1][r]),
                               fminf(red1[half * 4 + 2][r], red1[half * 4 + 3][r]));
        const float p = __expf(-0.5f * (acc[r] - gm));   // stable: dist - min(dist)
        acc[r] = p;
        float s = p;
        #pragma unroll
        for (int msk = 32; msk >= 1; msk >>= 1) s += __shfl_xor(s, msk);
        if ((tid & 63) == 0) red2[wv][r] = s;
    }
    __syncthreads();

    #pragma unroll
    for (int r = 0; r < 8; ++r) {
        const float den = red2[half * 4 + 0][r] + red2[half * 4 + 1][r] +
                          red2[half * 4 + 2][r] + red2[half * 4 + 3][r];
        const float inv = 1.0f / den;
        out[(size_t)(b0 + half * 8 + r) * Kn + k] = acc[r] * inv;
    }
}

// ---------------------------------------------------------------------------
// Fallback (round-1 kernel, known-good) if ws is too small.
// ---------------------------------------------------------------------------
constexpr int TB = 32, KC = 128, NCHUNK = Kn / KC, LSTR = 132;

__global__ __launch_bounds__(256, 1)
void gmm_soft_kernel(const float* __restrict__ z,
                     const float* __restrict__ cent,
                     const float* __restrict__ logvar,
                     float* __restrict__ out)
{
    __shared__ float zb[TB][LSTR];
    __shared__ float ssb[KC][LSTR];
    __shared__ float msb[KC][LSTR];

    const int tid = threadIdx.x;
    const int bq  = tid >> 5;
    const int kq  = tid & 31;
    const long b0 = (long)blockIdx.x * TB;

    #pragma unroll
    for (int i = 0; i < (TB * Dn / 4) / 256; ++i) {
        int idx = tid + i * 256;
        int row = idx >> 5, dg = idx & 31;
        float4 v = *reinterpret_cast<const float4*>(z + (b0 + row) * Dn + dg * 4);
        *reinterpret_cast<float4*>(&zb[row][dg * 4]) = v;
    }

    float acc[NCHUNK][4][4];
    #pragma unroll
    for (int c = 0; c < NCHUNK; ++c)
        #pragma unroll
        for (int bi = 0; bi < 4; ++bi)
            #pragma unroll
            for (int ki = 0; ki < 4; ++ki) acc[c][bi][ki] = 0.0f;

    for (int c = 0; c < NCHUNK; ++c) {
        __syncthreads();
        #pragma unroll
        for (int i = 0; i < (KC * Dn / 4) / 256; ++i) {
            int idx = tid + i * 256;
            int kl = idx >> 5, dg = idx & 31;
            const float4 cv = *reinterpret_cast<const float4*>(cent   + (c * KC + kl) * Dn + dg * 4);
            const float4 lv = *reinterpret_cast<const float4*>(logvar + (c * KC + kl) * Dn + dg * 4);
            float4 s, m;
            s.x = __expf(-0.5f * lv.x); m.x = cv.x * s.x;
            s.y = __expf(-0.5f * lv.y); m.y = cv.y * s.y;
            s.z = __expf(-0.5f * lv.z); m.z = cv.z * s.z;
            s.w = __expf(-0.5f * lv.w); m.w = cv.w * s.w;
            *reinterpret_cast<float4*>(&ssb[kl][dg * 4]) = s;
            *reinterpret_cast<float4*>(&msb[kl][dg * 4]) = m;
        }
        __syncthreads();

        #pragma unroll 2
        for (int dg = 0; dg < Dn / 4; ++dg) {
            float4 z4[4];
            #pragma unroll
            for (int bi = 0; bi < 4; ++bi)
                z4[bi] = *reinterpret_cast<const float4*>(&zb[bq * 4 + bi][dg * 4]);
            #pragma unroll
            for (int ki = 0; ki < 4; ++ki) {
                const int kl = ki * 32 + kq;
                const float4 s4 = *reinterpret_cast<const float4*>(&ssb[kl][dg * 4]);
                const float4 m4 = *reinterpret_cast<const float4*>(&msb[kl][dg * 4]);
                #pragma unroll
                for (int bi = 0; bi < 4; ++bi) {
                    float t0 = fmaf(z4[bi].x, s4.x, -m4.x);
                    float t1 = fmaf(z4[bi].y, s4.y, -m4.y);
                    float t2 = fmaf(z4[bi].z, s4.z, -m4.z);
                    float t3 = fmaf(z4[bi].w, s4.w, -m4.w);
                    float a = acc[c][bi][ki];
                    a = fmaf(t0, t0, a); a = fmaf(t1, t1, a);
                    a = fmaf(t2, t2, a); a = fmaf(t3, t3, a);
                    acc[c][bi][ki] = a;
                }
            }
        }
    }

    #pragma unroll
    for (int bi = 0; bi < 4; ++bi) {
        float dmin = acc[0][bi][0];
        #pragma unroll
        for (int c = 0; c < NCHUNK; ++c)
            #pragma unroll
            for (int ki = 0; ki < 4; ++ki) dmin = fminf(dmin, acc[c][bi][ki]);
        #pragma unroll
        for (int msk = 16; msk >= 1; msk >>= 1) dmin = fminf(dmin, __shfl_xor(dmin, msk));

        float p[NCHUNK][4];
        float ssum = 0.0f;
        #pragma unroll
        for (int c = 0; c < NCHUNK; ++c)
            #pragma unroll
            for (int ki = 0; ki < 4; ++ki) {
                p[c][ki] = __expf(-0.5f * (acc[c][bi][ki] - dmin));
                ssum += p[c][ki];
            }
        #pragma unroll
        for (int msk = 16; msk >= 1; msk >>= 1) ssum += __shfl_xor(ssum, msk);

        const float inv = 1.0f / ssum;
        const long b = b0 + bq * 4 + bi;
        #pragma unroll
        for (int c = 0; c < NCHUNK; ++c)
            #pragma unroll
            for (int ki = 0; ki < 4; ++ki)
                out[b * Kn + c * KC + ki * 32 + kq] = p[c][ki] * inv;
    }
}

extern "C" void kernel_launch(void* const* d_in, const int* in_sizes, int n_in,
                              void* d_out, int out_size, void* d_ws, size_t ws_size,
                              hipStream_t stream) {
    const float* z      = (const float*)d_in[0];
    const float* cent   = (const float*)d_in[1];
    const float* logvar = (const float*)d_in[2];
    float* out = (float*)d_out;
    (void)in_sizes; (void)n_in; (void)out_size;

    if (ws_size >= NEED_BYTES) {
        float* ws = (float*)d_ws;
        hipLaunchKernelGGL(prep_kernel, dim3(1024 + Kn / 8), dim3(256), 0, stream,
                           z, cent, logvar, ws);
        hipLaunchKernelGGL(gmm_main, dim3(Bn / 16), dim3(512), 0, stream,
                           (const float*)ws, out);
    } else {
        hipLaunchKernelGGL(gmm_soft_kernel, dim3(Bn / TB), dim3(256), 0, stream,
                           z, cent, logvar, out);
    }
}

// Round 4
// 30.876 us; speedup vs baseline: 2.1771x; 2.1771x over previous
//
#include <hip/hip_runtime.h>

// ---------------------------------------------------------------------------
// dist[b,k] = sum_d (z-mu)^2/var  =  sum_f F[b,f]*C[k,f] + c[k]
//   F = [z^2, z] interleaved (B x 256), C = [a, -2*mu*a] (K x 256),
//   a = exp(-logvar), c[k] = sum_d mu^2*a.
// out = softmax_k(-0.5*dist), fused in the GEMM epilogue (block owns all K).
// bf16 split precision: X = Xhi + Xlo; dist = Ah*Bh + Ah*Bl + Al*Bh (3 passes).
// ---------------------------------------------------------------------------

typedef short     bf16x8  __attribute__((ext_vector_type(8)));
typedef float     f32x4   __attribute__((ext_vector_type(4)));
typedef unsigned short ushort_t;
typedef ushort_t  ushort8 __attribute__((ext_vector_type(8)));

constexpr int Bn = 8192, Kn = 256, Dn = 128, Fn = 2 * Dn;   // Fn = 256 features

// ws layout, in ushort units: Fhi | Flo | Chi | Clo | cvec(f32)
constexpr size_t FHI_OFF = 0;
constexpr size_t FLO_OFF = (size_t)Bn * Fn;
constexpr size_t CHI_OFF = 2 * (size_t)Bn * Fn;
constexpr size_t CLO_OFF = CHI_OFF + (size_t)Kn * Fn;
constexpr size_t CV_OFF  = CLO_OFF + (size_t)Kn * Fn;
constexpr size_t NEED_BYTES = CV_OFF * 2 + (size_t)Kn * 4;

__device__ __forceinline__ ushort_t bf16_rn(float x) {
    unsigned u = __float_as_uint(x);
    u = (u + 0x7FFFu + ((u >> 16) & 1u)) >> 16;
    return (ushort_t)u;
}
__device__ __forceinline__ float bf16f(ushort_t h) {
    return __uint_as_float(((unsigned)h) << 16);
}

// ---------------------------------------------------------------------------
// Prep: build split-precision feature/coeff matrices + c[k].
// blocks 0..1023: z features; blocks 1024..1055: coefficients.
// ---------------------------------------------------------------------------
__global__ __launch_bounds__(256)
void prep(const float* __restrict__ z, const float* __restrict__ cent,
          const float* __restrict__ lvar, ushort_t* __restrict__ ws)
{
    const int tid = threadIdx.x, blk = blockIdx.x;
    if (blk < 1024) {
        const size_t i = (size_t)blk * 256 + tid;          // float4 index into z
        const float4 v = reinterpret_cast<const float4*>(z)[i];
        float f[8] = {v.x * v.x, v.x, v.y * v.y, v.y,
                      v.z * v.z, v.z, v.w * v.w, v.w};
        ushort8 hi, lo;
        #pragma unroll
        for (int j = 0; j < 8; ++j) {
            ushort_t h = bf16_rn(f[j]);
            hi[j] = h;
            lo[j] = bf16_rn(f[j] - bf16f(h));
        }
        *reinterpret_cast<ushort8*>(ws + FHI_OFF + i * 8) = hi;
        *reinterpret_cast<ushort8*>(ws + FLO_OFF + i * 8) = lo;
    } else {
        const int k  = (blk - 1024) * 8 + (tid >> 5);
        const int dq = tid & 31;
        const float4 cv = *reinterpret_cast<const float4*>(cent + (size_t)k * Dn + dq * 4);
        const float4 l4 = *reinterpret_cast<const float4*>(lvar + (size_t)k * Dn + dq * 4);
        const float a0 = expf(-l4.x), a1 = expf(-l4.y);
        const float a2 = expf(-l4.z), a3 = expf(-l4.w);
        float f[8] = {a0, -2.0f * cv.x * a0, a1, -2.0f * cv.y * a1,
                      a2, -2.0f * cv.z * a2, a3, -2.0f * cv.w * a3};
        ushort8 hi, lo;
        #pragma unroll
        for (int j = 0; j < 8; ++j) {
            ushort_t h = bf16_rn(f[j]);
            hi[j] = h;
            lo[j] = bf16_rn(f[j] - bf16f(h));
        }
        const size_t off = (size_t)k * Fn + dq * 8;
        *reinterpret_cast<ushort8*>(ws + CHI_OFF + off) = hi;
        *reinterpret_cast<ushort8*>(ws + CLO_OFF + off) = lo;

        float cp = cv.x * cv.x * a0 + cv.y * cv.y * a1 +
                   cv.z * cv.z * a2 + cv.w * cv.w * a3;
        #pragma unroll
        for (int m = 16; m >= 1; m >>= 1) cp += __shfl_xor(cp, m);
        if (dq == 0) reinterpret_cast<float*>(ws + CV_OFF)[k] = cp;
    }
}

// ---------------------------------------------------------------------------
// Main: 256 blocks x 512 thr (8 waves). Block = 32 b-rows x all 256 clusters.
// Wave w owns cols [w*32, w*32+32): 2 mi x 2 ni tiles of 16x16x32 bf16 MFMA,
// 3 split-precision passes accumulated into the same acc. Softmax in epilogue.
// MFMA layouts: A row=lane&15, k=(lane>>4)*8+j; B col=lane&15, same k;
// C/D col=lane&15, row=(lane>>4)*4+reg  [m89-verified].
// ---------------------------------------------------------------------------
__global__ __launch_bounds__(512, 2)
void mfma_main(const ushort_t* __restrict__ ws, float* __restrict__ out)
{
    const ushort_t* Fh = ws + FHI_OFF;
    const ushort_t* Fl = ws + FLO_OFF;
    const ushort_t* Ch = ws + CHI_OFF;
    const ushort_t* Cl = ws + CLO_OFF;
    const float*  cvec = reinterpret_cast<const float*>(ws + CV_OFF);

    const int tid = threadIdx.x;
    const int w   = tid >> 6;        // wave 0..7
    const int l   = tid & 63;
    const int lg  = l >> 4;          // 0..3
    const int ll  = l & 15;
    const int b0  = blockIdx.x * 32;
    const int n0  = w * 32;
    const int ks  = lg * 8;          // k-offset within a 32-wide K step

    f32x4 acc[2][2];
    #pragma unroll
    for (int mi = 0; mi < 2; ++mi)
        #pragma unroll
        for (int ni = 0; ni < 2; ++ni)
            acc[mi][ni] = (f32x4){0.f, 0.f, 0.f, 0.f};

    const size_t ar0 = (size_t)(b0 + ll) * Fn + ks;
    const size_t ar1 = ar0 + (size_t)16 * Fn;
    const size_t br0 = (size_t)(n0 + ll) * Fn + ks;
    const size_t br1 = br0 + (size_t)16 * Fn;

    #pragma unroll
    for (int kk = 0; kk < 8; ++kk) {
        const size_t o = (size_t)kk * 32;
        const bf16x8 a0h = *reinterpret_cast<const bf16x8*>(Fh + ar0 + o);
        const bf16x8 a1h = *reinterpret_cast<const bf16x8*>(Fh + ar1 + o);
        const bf16x8 a0l = *reinterpret_cast<const bf16x8*>(Fl + ar0 + o);
        const bf16x8 a1l = *reinterpret_cast<const bf16x8*>(Fl + ar1 + o);
        const bf16x8 b0h = *reinterpret_cast<const bf16x8*>(Ch + br0 + o);
        const bf16x8 b1h = *reinterpret_cast<const bf16x8*>(Ch + br1 + o);
        const bf16x8 b0l = *reinterpret_cast<const bf16x8*>(Cl + br0 + o);
        const bf16x8 b1l = *reinterpret_cast<const bf16x8*>(Cl + br1 + o);

        acc[0][0] = __builtin_amdgcn_mfma_f32_16x16x32_bf16(a0h, b0h, acc[0][0], 0, 0, 0);
        acc[0][1] = __builtin_amdgcn_mfma_f32_16x16x32_bf16(a0h, b1h, acc[0][1], 0, 0, 0);
        acc[1][0] = __builtin_amdgcn_mfma_f32_16x16x32_bf16(a1h, b0h, acc[1][0], 0, 0, 0);
        acc[1][1] = __builtin_amdgcn_mfma_f32_16x16x32_bf16(a1h, b1h, acc[1][1], 0, 0, 0);

        acc[0][0] = __builtin_amdgcn_mfma_f32_16x16x32_bf16(a0h, b0l, acc[0][0], 0, 0, 0);
        acc[0][1] = __builtin_amdgcn_mfma_f32_16x16x32_bf16(a0h, b1l, acc[0][1], 0, 0, 0);
        acc[1][0] = __builtin_amdgcn_mfma_f32_16x16x32_bf16(a1h, b0l, acc[1][0], 0, 0, 0);
        acc[1][1] = __builtin_amdgcn_mfma_f32_16x16x32_bf16(a1h, b1l, acc[1][1], 0, 0, 0);

        acc[0][0] = __builtin_amdgcn_mfma_f32_16x16x32_bf16(a0l, b0h, acc[0][0], 0, 0, 0);
        acc[0][1] = __builtin_amdgcn_mfma_f32_16x16x32_bf16(a0l, b1h, acc[0][1], 0, 0, 0);
        acc[1][0] = __builtin_amdgcn_mfma_f32_16x16x32_bf16(a1l, b0h, acc[1][0], 0, 0, 0);
        acc[1][1] = __builtin_amdgcn_mfma_f32_16x16x32_bf16(a1l, b1h, acc[1][1], 0, 0, 0);
    }

    // ---- epilogue: dist = acc + c[k]; softmax over k. 8 waves x 32 cols = 256.
    //      red[row][wave] partials; EXACTLY 8 wave slots (bug fix from round 3).
    __shared__ float red[32][8];

    const float ck0 = cvec[n0 + ll];
    const float ck1 = cvec[n0 + 16 + ll];

    float dv[2][2][4];
    #pragma unroll
    for (int mi = 0; mi < 2; ++mi)
        #pragma unroll
        for (int ni = 0; ni < 2; ++ni)
            #pragma unroll
            for (int r = 0; r < 4; ++r)
                dv[mi][ni][r] = acc[mi][ni][r] + (ni ? ck1 : ck0);

    // row-min over this wave's 32 cols (16 lanes of a group hold cols of one row)
    #pragma unroll
    for (int mi = 0; mi < 2; ++mi)
        #pragma unroll
        for (int r = 0; r < 4; ++r) {
            float t = fminf(dv[mi][0][r], dv[mi][1][r]);
            t = fminf(t, __shfl_xor(t, 1));
            t = fminf(t, __shfl_xor(t, 2));
            t = fminf(t, __shfl_xor(t, 4));
            t = fminf(t, __shfl_xor(t, 8));
            if (ll == 0) red[mi * 16 + lg * 4 + r][w] = t;
        }
    __syncthreads();

    float gm[2][4];
    #pragma unroll
    for (int mi = 0; mi < 2; ++mi)
        #pragma unroll
        for (int r = 0; r < 4; ++r) {
            const int row = mi * 16 + lg * 4 + r;
            const f32x4* rp = reinterpret_cast<const f32x4*>(&red[row][0]);
            f32x4 m4 = rp[0];
            {
                f32x4 v = rp[1];
                m4[0] = fminf(m4[0], v[0]); m4[1] = fminf(m4[1], v[1]);
                m4[2] = fminf(m4[2], v[2]); m4[3] = fminf(m4[3], v[3]);
            }
            gm[mi][r] = fminf(fminf(m4[0], m4[1]), fminf(m4[2], m4[3]));
        }
    __syncthreads();   // red reads done before reuse

    float pv[2][2][4];
    #pragma unroll
    for (int mi = 0; mi < 2; ++mi)
        #pragma unroll
        for (int r = 0; r < 4; ++r) {
            #pragma unroll
            for (int ni = 0; ni < 2; ++ni)
                pv[mi][ni][r] = __expf(-0.5f * (dv[mi][ni][r] - gm[mi][r]));
            float s = pv[mi][0][r] + pv[mi][1][r];
            s += __shfl_xor(s, 1);
            s += __shfl_xor(s, 2);
            s += __shfl_xor(s, 4);
            s += __shfl_xor(s, 8);
            if (ll == 0) red[mi * 16 + lg * 4 + r][w] = s;
        }
    __syncthreads();

    #pragma unroll
    for (int mi = 0; mi < 2; ++mi)
        #pragma unroll
        for (int r = 0; r < 4; ++r) {
            const int row = mi * 16 + lg * 4 + r;
            const f32x4* rp = reinterpret_cast<const f32x4*>(&red[row][0]);
            f32x4 s4 = rp[0];
            {
                f32x4 v = rp[1];
                s4[0] += v[0]; s4[1] += v[1]; s4[2] += v[2]; s4[3] += v[3];
            }
            const float inv = 1.0f / ((s4[0] + s4[1]) + (s4[2] + s4[3]));
            #pragma unroll
            for (int ni = 0; ni < 2; ++ni)
                out[(size_t)(b0 + row) * Kn + n0 + ni * 16 + ll] = pv[mi][ni][r] * inv;
        }
}

// ---------------------------------------------------------------------------
// Fallback (round-1 kernel, known-good, 29us) if ws too small.
// ---------------------------------------------------------------------------
constexpr int TB = 32, KC = 128, NCHUNK = Kn / KC, LSTR = 132;

__global__ __launch_bounds__(256, 1)
void gmm_soft_kernel(const float* __restrict__ z,
                     const float* __restrict__ cent,
                     const float* __restrict__ logvar,
                     float* __restrict__ out)
{
    __shared__ float zb[TB][LSTR];
    __shared__ float ssb[KC][LSTR];
    __shared__ float msb[KC][LSTR];

    const int tid = threadIdx.x;
    const int bq  = tid >> 5;
    const int kq  = tid & 31;
    const long b0 = (long)blockIdx.x * TB;

    #pragma unroll
    for (int i = 0; i < (TB * Dn / 4) / 256; ++i) {
        int idx = tid + i * 256;
        int row = idx >> 5, dg = idx & 31;
        float4 v = *reinterpret_cast<const float4*>(z + (b0 + row) * Dn + dg * 4);
        *reinterpret_cast<float4*>(&zb[row][dg * 4]) = v;
    }

    float acc[NCHUNK][4][4];
    #pragma unroll
    for (int c = 0; c < NCHUNK; ++c)
        #pragma unroll
        for (int bi = 0; bi < 4; ++bi)
            #pragma unroll
            for (int ki = 0; ki < 4; ++ki) acc[c][bi][ki] = 0.0f;

    for (int c = 0; c < NCHUNK; ++c) {
        __syncthreads();
        #pragma unroll
        for (int i = 0; i < (KC * Dn / 4) / 256; ++i) {
            int idx = tid + i * 256;
            int kl = idx >> 5, dg = idx & 31;
            const float4 cv = *reinterpret_cast<const float4*>(cent   + (c * KC + kl) * Dn + dg * 4);
            const float4 lv = *reinterpret_cast<const float4*>(logvar + (c * KC + kl) * Dn + dg * 4);
            float4 s, m;
            s.x = __expf(-0.5f * lv.x); m.x = cv.x * s.x;
            s.y = __expf(-0.5f * lv.y); m.y = cv.y * s.y;
            s.z = __expf(-0.5f * lv.z); m.z = cv.z * s.z;
            s.w = __expf(-0.5f * lv.w); m.w = cv.w * s.w;
            *reinterpret_cast<float4*>(&ssb[kl][dg * 4]) = s;
            *reinterpret_cast<float4*>(&msb[kl][dg * 4]) = m;
        }
        __syncthreads();

        #pragma unroll 2
        for (int dg = 0; dg < Dn / 4; ++dg) {
            float4 z4[4];
            #pragma unroll
            for (int bi = 0; bi < 4; ++bi)
                z4[bi] = *reinterpret_cast<const float4*>(&zb[bq * 4 + bi][dg * 4]);
            #pragma unroll
            for (int ki = 0; ki < 4; ++ki) {
                const int kl = ki * 32 + kq;
                const float4 s4 = *reinterpret_cast<const float4*>(&ssb[kl][dg * 4]);
                const float4 m4 = *reinterpret_cast<const float4*>(&msb[kl][dg * 4]);
                #pragma unroll
                for (int bi = 0; bi < 4; ++bi) {
                    float t0 = fmaf(z4[bi].x, s4.x, -m4.x);
                    float t1 = fmaf(z4[bi].y, s4.y, -m4.y);
                    float t2 = fmaf(z4[bi].z, s4.z, -m4.z);
                    float t3 = fmaf(z4[bi].w, s4.w, -m4.w);
                    float a = acc[c][bi][ki];
                    a = fmaf(t0, t0, a); a = fmaf(t1, t1, a);
                    a = fmaf(t2, t2, a); a = fmaf(t3, t3, a);
                    acc[c][bi][ki] = a;
                }
            }
        }
    }

    #pragma unroll
    for (int bi = 0; bi < 4; ++bi) {
        float dmin = acc[0][bi][0];
        #pragma unroll
        for (int c = 0; c < NCHUNK; ++c)
            #pragma unroll
            for (int ki = 0; ki < 4; ++ki) dmin = fminf(dmin, acc[c][bi][ki]);
        #pragma unroll
        for (int msk = 16; msk >= 1; msk >>= 1) dmin = fminf(dmin, __shfl_xor(dmin, msk));

        float p[NCHUNK][4];
        float ssum = 0.0f;
        #pragma unroll
        for (int c = 0; c < NCHUNK; ++c)
            #pragma unroll
            for (int ki = 0; ki < 4; ++ki) {
                p[c][ki] = __expf(-0.5f * (acc[c][bi][ki] - dmin));
                ssum += p[c][ki];
            }
        #pragma unroll
        for (int msk = 16; msk >= 1; msk >>= 1) ssum += __shfl_xor(ssum, msk);

        const float inv = 1.0f / ssum;
        const long b = b0 + bq * 4 + bi;
        #pragma unroll
        for (int c = 0; c < NCHUNK; ++c)
            #pragma unroll
            for (int ki = 0; ki < 4; ++ki)
                out[b * Kn + c * KC + ki * 32 + kq] = p[c][ki] * inv;
    }
}

extern "C" void kernel_launch(void* const* d_in, const int* in_sizes, int n_in,
                              void* d_out, int out_size, void* d_ws, size_t ws_size,
                              hipStream_t stream) {
    const float* z      = (const float*)d_in[0];
    const float* cent   = (const float*)d_in[1];
    const float* logvar = (const float*)d_in[2];
    float* out = (float*)d_out;
    (void)in_sizes; (void)n_in; (void)out_size;

    if (ws_size >= NEED_BYTES) {
        ushort_t* ws = (ushort_t*)d_ws;
        hipLaunchKernelGGL(prep, dim3(1024 + Kn / 8), dim3(256), 0, stream,
                           z, cent, logvar, ws);
        hipLaunchKernelGGL(mfma_main, dim3(Bn / 32), dim3(512), 0, stream,
                           (const ushort_t*)ws, out);
    } else {
        hipLaunchKernelGGL(gmm_soft_kernel, dim3(Bn / TB), dim3(256), 0, stream,
                           z, cent, logvar, out);
    }
}

// Round 5
// 26.841 us; speedup vs baseline: 2.5044x; 1.1503x over previous
//
#include <hip/hip_runtime.h>

// ---------------------------------------------------------------------------
// dist[b,k] = sum_d (z-mu)^2/var = sum_f F[b,f]*C[k,f] + c[k]
//   F = [z^2, z] interleaved (B x 256)  — built IN-KERNEL into LDS (hi/lo bf16)
//   C = [a, -2*mu*a] (K x 256), a = exp(-logvar); c[k] = sum_d mu^2*a  (prep)
// out = softmax_k(-0.5*dist), fused in the GEMM epilogue (block owns all K).
// Split precision: X = Xhi + Xlo (bf16); dist = Ah*Bh + Ah*Bl + Al*Bh.
// ---------------------------------------------------------------------------

typedef short     bf16x8  __attribute__((ext_vector_type(8)));
typedef float     f32x4   __attribute__((ext_vector_type(4)));
typedef unsigned short ushort_t;
typedef ushort_t  ushort8 __attribute__((ext_vector_type(8)));

constexpr int Bn = 8192, Kn = 256, Dn = 128, Fn = 2 * Dn;   // Fn = 256 features

// ws layout (ushort units): Chi | Clo | cvec(f32)
constexpr size_t CHI_OFF = 0;
constexpr size_t CLO_OFF = (size_t)Kn * Fn;          // 65536
constexpr size_t CV_OFF  = 2 * (size_t)Kn * Fn;      // 131072
constexpr size_t NEED_BYTES = CV_OFF * 2 + (size_t)Kn * 4;

__device__ __forceinline__ ushort_t bf16_rn(float x) {
    unsigned u = __float_as_uint(x);
    u = (u + 0x7FFFu + ((u >> 16) & 1u)) >> 16;
    return (ushort_t)u;
}
__device__ __forceinline__ float bf16f(ushort_t h) {
    return __uint_as_float(((unsigned)h) << 16);
}

// ---------------------------------------------------------------------------
// Prep: coefficient matrices Chi/Clo + cvec. 32 blocks x 256 thr.
// ---------------------------------------------------------------------------
__global__ __launch_bounds__(256)
void prep(const float* __restrict__ cent, const float* __restrict__ lvar,
          ushort_t* __restrict__ ws)
{
    const int tid = threadIdx.x;
    const int k   = blockIdx.x * 8 + (tid >> 5);
    const int dq  = tid & 31;
    const float4 cv = *reinterpret_cast<const float4*>(cent + (size_t)k * Dn + dq * 4);
    const float4 l4 = *reinterpret_cast<const float4*>(lvar + (size_t)k * Dn + dq * 4);
    const float a0 = expf(-l4.x), a1 = expf(-l4.y);
    const float a2 = expf(-l4.z), a3 = expf(-l4.w);
    float f[8] = {a0, -2.0f * cv.x * a0, a1, -2.0f * cv.y * a1,
                  a2, -2.0f * cv.z * a2, a3, -2.0f * cv.w * a3};
    ushort8 hi, lo;
    #pragma unroll
    for (int j = 0; j < 8; ++j) {
        ushort_t h = bf16_rn(f[j]);
        hi[j] = h;
        lo[j] = bf16_rn(f[j] - bf16f(h));
    }
    const size_t off = (size_t)k * Fn + dq * 8;
    *reinterpret_cast<ushort8*>(ws + CHI_OFF + off) = hi;
    *reinterpret_cast<ushort8*>(ws + CLO_OFF + off) = lo;

    float cp = cv.x * cv.x * a0 + cv.y * cv.y * a1 +
               cv.z * cv.z * a2 + cv.w * cv.w * a3;
    #pragma unroll
    for (int m = 16; m >= 1; m >>= 1) cp += __shfl_xor(cp, m);
    if (dq == 0) reinterpret_cast<float*>(ws + CV_OFF)[k] = cp;
}

// ---------------------------------------------------------------------------
// Main: 256 blocks x 1024 thr (16 waves, 4 waves/SIMD). Block = 32 b-rows x
// all 256 clusters. Wave w owns cols [w*16, w*16+16): 2 mi x 1 ni tiles of
// 16x16x32 bf16 MFMA, 3 split passes -> 48 MFMA/wave. A staged in LDS
// (XOR-swizzled), B loaded from global (L2-resident, prefetched 1 kk ahead).
// MFMA layouts: A row=lane&15, k=(lane>>4)*8+j; B col=lane&15, same k;
// C/D col=lane&15, row=(lane>>4)*4+reg  [m89-verified].
// ---------------------------------------------------------------------------
__global__ __launch_bounds__(1024, 4)
void mfma_main(const float* __restrict__ z, const ushort_t* __restrict__ ws,
               float* __restrict__ out)
{
    __shared__ ushort_t Ah[32 * 256];   // 16 KB
    __shared__ ushort_t Al[32 * 256];   // 16 KB
    __shared__ float red[32][16];       // 2 KB

    const ushort_t* Ch = ws + CHI_OFF;
    const ushort_t* Cl = ws + CLO_OFF;
    const float*  cvec = reinterpret_cast<const float*>(ws + CV_OFF);

    const int tid = threadIdx.x;
    const int w   = tid >> 6;        // wave 0..15
    const int l   = tid & 63;
    const int lg  = l >> 4;          // 0..3
    const int ll  = l & 15;
    const int b0  = blockIdx.x * 32;
    const int n0  = w * 16;

    // ---- build A = [z^2, z] hi/lo into LDS (swizzled) ----
    {
        const int row = tid >> 5;    // 0..31
        const int dq  = tid & 31;    // float4 within row
        const float4 v = *reinterpret_cast<const float4*>(z + (size_t)(b0 + row) * Dn + dq * 4);
        float f[8] = {v.x * v.x, v.x, v.y * v.y, v.y,
                      v.z * v.z, v.z, v.w * v.w, v.w};
        ushort8 hi, lo;
        #pragma unroll
        for (int j = 0; j < 8; ++j) {
            ushort_t h = bf16_rn(f[j]);
            hi[j] = h;
            lo[j] = bf16_rn(f[j] - bf16f(h));
        }
        const int off = (row * 256 + dq * 8) ^ ((row & 7) << 3);   // ushort units
        *reinterpret_cast<ushort8*>(&Ah[off]) = hi;
        *reinterpret_cast<ushort8*>(&Al[off]) = lo;
    }
    __syncthreads();

    // ---- GEMM: acc[mi] for rows (ll, 16+ll) x cols n0+ll ----
    f32x4 acc0 = (f32x4){0.f, 0.f, 0.f, 0.f};
    f32x4 acc1 = (f32x4){0.f, 0.f, 0.f, 0.f};

    const size_t br = (size_t)(n0 + ll) * Fn + lg * 8;
    const int ar0 = ll * 256 + lg * 8;          // row = ll
    const int ar1 = (16 + ll) * 256 + lg * 8;   // row = 16+ll
    const int sw0 = (ll & 7) << 3;
    const int sw1 = ((16 + ll) & 7) << 3;       // == sw0, rows 16..31 alias 0..7 pattern

    bf16x8 bh = *reinterpret_cast<const bf16x8*>(Ch + br);
    bf16x8 bl = *reinterpret_cast<const bf16x8*>(Cl + br);

    #pragma unroll
    for (int kk = 0; kk < 8; ++kk) {
        bf16x8 nbh, nbl;
        if (kk < 7) {
            nbh = *reinterpret_cast<const bf16x8*>(Ch + br + (kk + 1) * 32);
            nbl = *reinterpret_cast<const bf16x8*>(Cl + br + (kk + 1) * 32);
        }
        const int o = kk * 32;
        const bf16x8 a0h = *reinterpret_cast<const bf16x8*>(&Ah[(ar0 + o) ^ sw0]);
        const bf16x8 a0l = *reinterpret_cast<const bf16x8*>(&Al[(ar0 + o) ^ sw0]);
        const bf16x8 a1h = *reinterpret_cast<const bf16x8*>(&Ah[(ar1 + o) ^ sw1]);
        const bf16x8 a1l = *reinterpret_cast<const bf16x8*>(&Al[(ar1 + o) ^ sw1]);

        acc0 = __builtin_amdgcn_mfma_f32_16x16x32_bf16(a0h, bh, acc0, 0, 0, 0);
        acc1 = __builtin_amdgcn_mfma_f32_16x16x32_bf16(a1h, bh, acc1, 0, 0, 0);
        acc0 = __builtin_amdgcn_mfma_f32_16x16x32_bf16(a0h, bl, acc0, 0, 0, 0);
        acc1 = __builtin_amdgcn_mfma_f32_16x16x32_bf16(a1h, bl, acc1, 0, 0, 0);
        acc0 = __builtin_amdgcn_mfma_f32_16x16x32_bf16(a0l, bh, acc0, 0, 0, 0);
        acc1 = __builtin_amdgcn_mfma_f32_16x16x32_bf16(a1l, bh, acc1, 0, 0, 0);

        bh = nbh; bl = nbl;
    }

    // ---- epilogue: dist = acc + c[k]; softmax over k (16 waves x 16 cols) ----
    const float ck = cvec[n0 + ll];
    float dv[2][4];
    #pragma unroll
    for (int r = 0; r < 4; ++r) { dv[0][r] = acc0[r] + ck; dv[1][r] = acc1[r] + ck; }

    // per-wave row-min over its 16 cols (lanes of one lg group = one row)
    #pragma unroll
    for (int mi = 0; mi < 2; ++mi)
        #pragma unroll
        for (int r = 0; r < 4; ++r) {
            float t = dv[mi][r];
            t = fminf(t, __shfl_xor(t, 1));
            t = fminf(t, __shfl_xor(t, 2));
            t = fminf(t, __shfl_xor(t, 4));
            t = fminf(t, __shfl_xor(t, 8));
            if (ll == 0) red[mi * 16 + lg * 4 + r][w] = t;
        }
    __syncthreads();

    float gm[2][4];
    #pragma unroll
    for (int mi = 0; mi < 2; ++mi)
        #pragma unroll
        for (int r = 0; r < 4; ++r) {
            const int row = mi * 16 + lg * 4 + r;
            const f32x4* rp = reinterpret_cast<const f32x4*>(&red[row][0]);
            f32x4 m4 = rp[0];
            #pragma unroll
            for (int q = 1; q < 4; ++q) {
                f32x4 v = rp[q];
                m4[0] = fminf(m4[0], v[0]); m4[1] = fminf(m4[1], v[1]);
                m4[2] = fminf(m4[2], v[2]); m4[3] = fminf(m4[3], v[3]);
            }
            gm[mi][r] = fminf(fminf(m4[0], m4[1]), fminf(m4[2], m4[3]));
        }
    __syncthreads();   // all red reads done before reuse

    float pv[2][4];
    #pragma unroll
    for (int mi = 0; mi < 2; ++mi)
        #pragma unroll
        for (int r = 0; r < 4; ++r) {
            const float p = __expf(-0.5f * (dv[mi][r] - gm[mi][r]));
            pv[mi][r] = p;
            float s = p;
            s += __shfl_xor(s, 1);
            s += __shfl_xor(s, 2);
            s += __shfl_xor(s, 4);
            s += __shfl_xor(s, 8);
            if (ll == 0) red[mi * 16 + lg * 4 + r][w] = s;
        }
    __syncthreads();

    #pragma unroll
    for (int mi = 0; mi < 2; ++mi)
        #pragma unroll
        for (int r = 0; r < 4; ++r) {
            const int row = mi * 16 + lg * 4 + r;
            const f32x4* rp = reinterpret_cast<const f32x4*>(&red[row][0]);
            f32x4 s4 = rp[0];
            #pragma unroll
            for (int q = 1; q < 4; ++q) {
                f32x4 v = rp[q];
                s4[0] += v[0]; s4[1] += v[1]; s4[2] += v[2]; s4[3] += v[3];
            }
            const float inv = 1.0f / ((s4[0] + s4[1]) + (s4[2] + s4[3]));
            out[(size_t)(b0 + row) * Kn + n0 + ll] = pv[mi][r] * inv;
        }
}

// ---------------------------------------------------------------------------
// Fallback (round-1 kernel, known-good, 29us) if ws too small.
// ---------------------------------------------------------------------------
constexpr int TB = 32, KC = 128, NCHUNK = Kn / KC, LSTR = 132;

__global__ __launch_bounds__(256, 1)
void gmm_soft_kernel(const float* __restrict__ z,
                     const float* __restrict__ cent,
                     const float* __restrict__ logvar,
                     float* __restrict__ out)
{
    __shared__ float zb[TB][LSTR];
    __shared__ float ssb[KC][LSTR];
    __shared__ float msb[KC][LSTR];

    const int tid = threadIdx.x;
    const int bq  = tid >> 5;
    const int kq  = tid & 31;
    const long b0 = (long)blockIdx.x * TB;

    #pragma unroll
    for (int i = 0; i < (TB * Dn / 4) / 256; ++i) {
        int idx = tid + i * 256;
        int row = idx >> 5, dg = idx & 31;
        float4 v = *reinterpret_cast<const float4*>(z + (b0 + row) * Dn + dg * 4);
        *reinterpret_cast<float4*>(&zb[row][dg * 4]) = v;
    }

    float acc[NCHUNK][4][4];
    #pragma unroll
    for (int c = 0; c < NCHUNK; ++c)
        #pragma unroll
        for (int bi = 0; bi < 4; ++bi)
            #pragma unroll
            for (int ki = 0; ki < 4; ++ki) acc[c][bi][ki] = 0.0f;

    for (int c = 0; c < NCHUNK; ++c) {
        __syncthreads();
        #pragma unroll
        for (int i = 0; i < (KC * Dn / 4) / 256; ++i) {
            int idx = tid + i * 256;
            int kl = idx >> 5, dg = idx & 31;
            const float4 cv = *reinterpret_cast<const float4*>(cent   + (c * KC + kl) * Dn + dg * 4);
            const float4 lv = *reinterpret_cast<const float4*>(logvar + (c * KC + kl) * Dn + dg * 4);
            float4 s, m;
            s.x = __expf(-0.5f * lv.x); m.x = cv.x * s.x;
            s.y = __expf(-0.5f * lv.y); m.y = cv.y * s.y;
            s.z = __expf(-0.5f * lv.z); m.z = cv.z * s.z;
            s.w = __expf(-0.5f * lv.w); m.w = cv.w * s.w;
            *reinterpret_cast<float4*>(&ssb[kl][dg * 4]) = s;
            *reinterpret_cast<float4*>(&msb[kl][dg * 4]) = m;
        }
        __syncthreads();

        #pragma unroll 2
        for (int dg = 0; dg < Dn / 4; ++dg) {
            float4 z4[4];
            #pragma unroll
            for (int bi = 0; bi < 4; ++bi)
                z4[bi] = *reinterpret_cast<const float4*>(&zb[bq * 4 + bi][dg * 4]);
            #pragma unroll
            for (int ki = 0; ki < 4; ++ki) {
                const int kl = ki * 32 + kq;
                const float4 s4 = *reinterpret_cast<const float4*>(&ssb[kl][dg * 4]);
                const float4 m4 = *reinterpret_cast<const float4*>(&msb[kl][dg * 4]);
                #pragma unroll
                for (int bi = 0; bi < 4; ++bi) {
                    float t0 = fmaf(z4[bi].x, s4.x, -m4.x);
                    float t1 = fmaf(z4[bi].y, s4.y, -m4.y);
                    float t2 = fmaf(z4[bi].z, s4.z, -m4.z);
                    float t3 = fmaf(z4[bi].w, s4.w, -m4.w);
                    float a = acc[c][bi][ki];
                    a = fmaf(t0, t0, a); a = fmaf(t1, t1, a);
                    a = fmaf(t2, t2, a); a = fmaf(t3, t3, a);
                    acc[c][bi][ki] = a;
                }
            }
        }
    }

    #pragma unroll
    for (int bi = 0; bi < 4; ++bi) {
        float dmin = acc[0][bi][0];
        #pragma unroll
        for (int c = 0; c < NCHUNK; ++c)
            #pragma unroll
            for (int ki = 0; ki < 4; ++ki) dmin = fminf(dmin, acc[c][bi][ki]);
        #pragma unroll
        for (int msk = 16; msk >= 1; msk >>= 1) dmin = fminf(dmin, __shfl_xor(dmin, msk));

        float p[NCHUNK][4];
        float ssum = 0.0f;
        #pragma unroll
        for (int c = 0; c < NCHUNK; ++c)
            #pragma unroll
            for (int ki = 0; ki < 4; ++ki) {
                p[c][ki] = __expf(-0.5f * (acc[c][bi][ki] - dmin));
                ssum += p[c][ki];
            }
        #pragma unroll
        for (int msk = 16; msk >= 1; msk >>= 1) ssum += __shfl_xor(ssum, msk);

        const float inv = 1.0f / ssum;
        const long b = b0 + bq * 4 + bi;
        #pragma unroll
        for (int c = 0; c < NCHUNK; ++c)
            #pragma unroll
            for (int ki = 0; ki < 4; ++ki)
                out[b * Kn + c * KC + ki * 32 + kq] = p[c][ki] * inv;
    }
}

extern "C" void kernel_launch(void* const* d_in, const int* in_sizes, int n_in,
                              void* d_out, int out_size, void* d_ws, size_t ws_size,
                              hipStream_t stream) {
    const float* z      = (const float*)d_in[0];
    const float* cent   = (const float*)d_in[1];
    const float* logvar = (const float*)d_in[2];
    float* out = (float*)d_out;
    (void)in_sizes; (void)n_in; (void)out_size;

    if (ws_size >= NEED_BYTES) {
        ushort_t* ws = (ushort_t*)d_ws;
        hipLaunchKernelGGL(prep, dim3(Kn / 8), dim3(256), 0, stream,
                           cent, logvar, ws);
        hipLaunchKernelGGL(mfma_main, dim3(Bn / 32), dim3(1024), 0, stream,
                           z, (const ushort_t*)ws, out);
    } else {
        hipLaunchKernelGGL(gmm_soft_kernel, dim3(Bn / TB), dim3(256), 0, stream,
                           z, cent, logvar, out);
    }
}

// Round 6
// 25.349 us; speedup vs baseline: 2.6519x; 1.0589x over previous
//
#include <hip/hip_runtime.h>

// ---------------------------------------------------------------------------
// Single fused kernel.
// dist[b,k] = sum_d (z-mu)^2/var = sum_f F[b,f]*C[k,f] + c[k]
//   F = [z^2, z] interleaved (B x 256)  — built in-kernel into LDS (hi/lo bf16)
//   C = [a, -2*mu*a] (K x 256), a = exp(-logvar) — built PER-WAVE in registers
//   c[k] = sum_d mu^2*a — per-lane partial + 2 shuffles.
// out = softmax_k(-0.5*dist) fused in the epilogue (block owns all 256 k).
// Split precision: X = Xhi + Xlo (bf16); dist = Ah*Bh + Ah*Bl + Al*Bh.
// MFMA 16x16x32 bf16 layouts [m89-verified]:
//   A: row=lane&15, k=(lane>>4)*8+j ; B: col=lane&15, same k ;
//   C/D: col=lane&15, row=(lane>>4)*4+reg.
// ---------------------------------------------------------------------------

typedef short     bf16x8  __attribute__((ext_vector_type(8)));
typedef float     f32x4   __attribute__((ext_vector_type(4)));
typedef unsigned short ushort_t;
typedef ushort_t  ushort8 __attribute__((ext_vector_type(8)));

constexpr int Bn = 8192, Kn = 256, Dn = 128;

__device__ __forceinline__ ushort_t bf16_rn(float x) {
    unsigned u = __float_as_uint(x);
    u = (u + 0x7FFFu + ((u >> 16) & 1u)) >> 16;
    return (ushort_t)u;
}
__device__ __forceinline__ float bf16f(ushort_t h) {
    return __uint_as_float(((unsigned)h) << 16);
}

__global__ __launch_bounds__(1024, 4)
void gmm_fused(const float* __restrict__ z, const float* __restrict__ cent,
               const float* __restrict__ lvar, float* __restrict__ out)
{
    __shared__ ushort_t Ah[32 * 256];   // 16 KB
    __shared__ ushort_t Al[32 * 256];   // 16 KB
    __shared__ float red[32][16];       // 2 KB

    const int tid = threadIdx.x;
    const int w   = tid >> 6;        // wave 0..15
    const int l   = tid & 63;
    const int lg  = l >> 4;          // 0..3
    const int ll  = l & 15;
    const int b0  = blockIdx.x * 32;
    const int n0  = w * 16;          // this wave's 16 cluster-cols

    // ---- phase 1: per-lane B-fragments (col n0+ll) in registers + c[k] ----
    // lane covers d = kk*16 + lg*4 + {0..3}, kk = 0..7
    bf16x8 Bh[8], Bl[8];
    float cpart = 0.0f;
    const size_t crow = (size_t)(n0 + ll) * Dn + lg * 4;
    #pragma unroll
    for (int kk = 0; kk < 8; ++kk) {
        const float4 cv = *reinterpret_cast<const float4*>(cent + crow + kk * 16);
        const float4 l4 = *reinterpret_cast<const float4*>(lvar + crow + kk * 16);
        const float a0 = __expf(-l4.x), a1 = __expf(-l4.y);
        const float a2 = __expf(-l4.z), a3 = __expf(-l4.w);
        const float f[8] = {a0, -2.0f * cv.x * a0, a1, -2.0f * cv.y * a1,
                            a2, -2.0f * cv.z * a2, a3, -2.0f * cv.w * a3};
        ushort8 hi8, lo8;
        #pragma unroll
        for (int j = 0; j < 8; ++j) {
            ushort_t h = bf16_rn(f[j]);
            hi8[j] = h;
            lo8[j] = bf16_rn(f[j] - bf16f(h));
        }
        Bh[kk] = (bf16x8)hi8;
        Bl[kk] = (bf16x8)lo8;
        cpart += cv.x * cv.x * a0 + cv.y * cv.y * a1 +
                 cv.z * cv.z * a2 + cv.w * cv.w * a3;
    }
    cpart += __shfl_xor(cpart, 16);
    cpart += __shfl_xor(cpart, 32);
    const float ck = cpart;          // c[n0+ll], matches C/D col=ll

    // ---- phase 2: A = [z^2, z] hi/lo into swizzled LDS ----
    {
        const int row = tid >> 5;    // 0..31
        const int dq  = tid & 31;    // float4 within row
        const float4 v = *reinterpret_cast<const float4*>(z + (size_t)(b0 + row) * Dn + dq * 4);
        const float f[8] = {v.x * v.x, v.x, v.y * v.y, v.y,
                            v.z * v.z, v.z, v.w * v.w, v.w};
        ushort8 hi8, lo8;
        #pragma unroll
        for (int j = 0; j < 8; ++j) {
            ushort_t h = bf16_rn(f[j]);
            hi8[j] = h;
            lo8[j] = bf16_rn(f[j] - bf16f(h));
        }
        const int off = (row * 256 + dq * 8) ^ ((row & 7) << 3);   // ushort units
        *reinterpret_cast<ushort8*>(&Ah[off]) = hi8;
        *reinterpret_cast<ushort8*>(&Al[off]) = lo8;
    }
    __syncthreads();

    // ---- phase 3: MFMA loop — pure LDS A reads, register B ----
    f32x4 acc0 = (f32x4){0.f, 0.f, 0.f, 0.f};
    f32x4 acc1 = (f32x4){0.f, 0.f, 0.f, 0.f};
    const int ar0 = ll * 256 + lg * 8;
    const int ar1 = ar0 + 16 * 256;
    const int sw  = (ll & 7) << 3;   // rows 16..31 have same (row&7) pattern

    #pragma unroll
    for (int kk = 0; kk < 8; ++kk) {
        const int o = kk * 32;
        const bf16x8 a0h = *reinterpret_cast<const bf16x8*>(&Ah[(ar0 + o) ^ sw]);
        const bf16x8 a0l = *reinterpret_cast<const bf16x8*>(&Al[(ar0 + o) ^ sw]);
        const bf16x8 a1h = *reinterpret_cast<const bf16x8*>(&Ah[(ar1 + o) ^ sw]);
        const bf16x8 a1l = *reinterpret_cast<const bf16x8*>(&Al[(ar1 + o) ^ sw]);

        acc0 = __builtin_amdgcn_mfma_f32_16x16x32_bf16(a0h, Bh[kk], acc0, 0, 0, 0);
        acc1 = __builtin_amdgcn_mfma_f32_16x16x32_bf16(a1h, Bh[kk], acc1, 0, 0, 0);
        acc0 = __builtin_amdgcn_mfma_f32_16x16x32_bf16(a0h, Bl[kk], acc0, 0, 0, 0);
        acc1 = __builtin_amdgcn_mfma_f32_16x16x32_bf16(a1h, Bl[kk], acc1, 0, 0, 0);
        acc0 = __builtin_amdgcn_mfma_f32_16x16x32_bf16(a0l, Bh[kk], acc0, 0, 0, 0);
        acc1 = __builtin_amdgcn_mfma_f32_16x16x32_bf16(a1l, Bh[kk], acc1, 0, 0, 0);
    }

    // ---- epilogue: dist = acc + ck; softmax over k (16 waves x 16 cols) ----
    float dv[2][4];
    #pragma unroll
    for (int r = 0; r < 4; ++r) { dv[0][r] = acc0[r] + ck; dv[1][r] = acc1[r] + ck; }

    #pragma unroll
    for (int mi = 0; mi < 2; ++mi)
        #pragma unroll
        for (int r = 0; r < 4; ++r) {
            float t = dv[mi][r];
            t = fminf(t, __shfl_xor(t, 1));
            t = fminf(t, __shfl_xor(t, 2));
            t = fminf(t, __shfl_xor(t, 4));
            t = fminf(t, __shfl_xor(t, 8));
            if (ll == 0) red[mi * 16 + lg * 4 + r][w] = t;
        }
    __syncthreads();

    float gm[2][4];
    #pragma unroll
    for (int mi = 0; mi < 2; ++mi)
        #pragma unroll
        for (int r = 0; r < 4; ++r) {
            const int row = mi * 16 + lg * 4 + r;
            const f32x4* rp = reinterpret_cast<const f32x4*>(&red[row][0]);
            f32x4 m4 = rp[0];
            #pragma unroll
            for (int q = 1; q < 4; ++q) {
                f32x4 v = rp[q];
                m4[0] = fminf(m4[0], v[0]); m4[1] = fminf(m4[1], v[1]);
                m4[2] = fminf(m4[2], v[2]); m4[3] = fminf(m4[3], v[3]);
            }
            gm[mi][r] = fminf(fminf(m4[0], m4[1]), fminf(m4[2], m4[3]));
        }
    __syncthreads();   // all red reads done before reuse

    float pv[2][4];
    #pragma unroll
    for (int mi = 0; mi < 2; ++mi)
        #pragma unroll
        for (int r = 0; r < 4; ++r) {
            const float p = __expf(-0.5f * (dv[mi][r] - gm[mi][r]));
            pv[mi][r] = p;
            float s = p;
            s += __shfl_xor(s, 1);
            s += __shfl_xor(s, 2);
            s += __shfl_xor(s, 4);
            s += __shfl_xor(s, 8);
            if (ll == 0) red[mi * 16 + lg * 4 + r][w] = s;
        }
    __syncthreads();

    #pragma unroll
    for (int mi = 0; mi < 2; ++mi)
        #pragma unroll
        for (int r = 0; r < 4; ++r) {
            const int row = mi * 16 + lg * 4 + r;
            const f32x4* rp = reinterpret_cast<const f32x4*>(&red[row][0]);
            f32x4 s4 = rp[0];
            #pragma unroll
            for (int q = 1; q < 4; ++q) {
                f32x4 v = rp[q];
                s4[0] += v[0]; s4[1] += v[1]; s4[2] += v[2]; s4[3] += v[3];
            }
            const float inv = 1.0f / ((s4[0] + s4[1]) + (s4[2] + s4[3]));
            out[(size_t)(b0 + row) * Kn + n0 + ll] = pv[mi][r] * inv;
        }
}

extern "C" void kernel_launch(void* const* d_in, const int* in_sizes, int n_in,
                              void* d_out, int out_size, void* d_ws, size_t ws_size,
                              hipStream_t stream) {
    const float* z      = (const float*)d_in[0];
    const float* cent   = (const float*)d_in[1];
    const float* logvar = (const float*)d_in[2];
    float* out = (float*)d_out;
    (void)in_sizes; (void)n_in; (void)out_size; (void)d_ws; (void)ws_size;

    hipLaunchKernelGGL(gmm_fused, dim3(Bn / 32), dim3(1024), 0, stream,
                       z, cent, logvar, out);
}

// Round 7
// 21.940 us; speedup vs baseline: 3.0639x; 1.1554x over previous
//
#include <hip/hip_runtime.h>
#include <hip/hip_bf16.h>

// ---------------------------------------------------------------------------
// Single fused kernel, round 7.
// dist[b,k] = sum_d (z-mu)^2/var = sum_f F[b,f]*C[k,f] + c[k]
//   F = [z^2, z] interleaved (B x 256) — staged in LDS as MFMA fragments,
//       FRAGMENT-ORDERED (lane-linear): slot = [region][kk][lane] * 16B, so
//       every ds_write_b128 / ds_read_b128 is base + lane*16B (zero-conflict,
//       measured-clean 12-cyc pattern per m134).
//   C = [a, -2*mu*a], a = exp(-logvar) — built per-kk IN the loop (registers),
//       cent/lvar prefetched 1 kk ahead; c[k] = sum_d mu^2*a via 2 shuffles.
// out = softmax_k(-0.5*dist) fused in the epilogue (block owns all 256 k).
// Split precision: X = Xhi + Xlo (bf16, RNE via v_cvt_pk_bf16_f32);
// dist = Ah*Bh + Ah*Bl + Al*Bh  (3 MFMA passes, f32 accumulate).
// MFMA 16x16x32 bf16 layouts [m89-verified]:
//   A: row=lane&15, k=(lane>>4)*8+j ; B: col=lane&15, same k ;
//   C/D: col=lane&15, row=(lane>>4)*4+reg.
// ---------------------------------------------------------------------------

typedef short     bf16x8  __attribute__((ext_vector_type(8)));
typedef float     f32x4   __attribute__((ext_vector_type(4)));
typedef unsigned short ushort_t;

constexpr int Bn = 8192, Kn = 256, Dn = 128;

__device__ __forceinline__ short bfbits(__hip_bfloat16 h) {
    return __builtin_bit_cast(short, h);
}

// 8 floats -> hi/lo bf16x8 via packed RNE converts (v_cvt_pk_bf16_f32)
__device__ __forceinline__ void split8(const float* f, bf16x8& hi, bf16x8& lo) {
    #pragma unroll
    for (int p = 0; p < 4; ++p) {
        const float2 fp = make_float2(f[2 * p], f[2 * p + 1]);
        const __hip_bfloat162 h2 = __float22bfloat162_rn(fp);
        hi[2 * p]     = bfbits(h2.x);
        hi[2 * p + 1] = bfbits(h2.y);
        const float2 rp = make_float2(fp.x - __bfloat162float(h2.x),
                                      fp.y - __bfloat162float(h2.y));
        const __hip_bfloat162 l2 = __float22bfloat162_rn(rp);
        lo[2 * p]     = bfbits(l2.x);
        lo[2 * p + 1] = bfbits(l2.y);
    }
}

__global__ __launch_bounds__(1024, 4)
void gmm_fused(const float* __restrict__ z, const float* __restrict__ cent,
               const float* __restrict__ lvar, float* __restrict__ out)
{
    // A fragments, fragment-ordered: [region(2)][kk(8)][lane(64)][8 ushort]
    __shared__ ushort_t Ah[2 * 8 * 64 * 8];   // 16 KB
    __shared__ ushort_t Al[2 * 8 * 64 * 8];   // 16 KB
    __shared__ float red[32][16];             // 2 KB

    const int tid = threadIdx.x;
    const int w   = tid >> 6;        // wave 0..15
    const int l   = tid & 63;
    const int lg  = l >> 4;          // 0..3
    const int ll  = l & 15;
    const int b0  = blockIdx.x * 32;
    const int n0  = w * 16;          // this wave's 16 cluster-cols

    // ---- stage A = [z^2, z] hi/lo, lane-linear fragment order ----
    // thread t -> (region r = t>>9, kk = (t>>6)&7, lane l = t&63):
    // slot holds F[row = r*16 + (l&15)][k = kk*32 + (l>>4)*8 + j], j=0..7
    // i.e. z[row][d0..d0+3] with d0 = kk*16 + (l>>4)*4.
    {
        const int r   = tid >> 9;
        const int kks = (tid >> 6) & 7;
        const int row = r * 16 + ll;
        const int d0  = kks * 16 + lg * 4;
        const float4 v = *reinterpret_cast<const float4*>(
            z + (size_t)(b0 + row) * Dn + d0);
        const float f[8] = {v.x * v.x, v.x, v.y * v.y, v.y,
                            v.z * v.z, v.z, v.w * v.w, v.w};
        bf16x8 hi, lo;
        split8(f, hi, lo);
        const int off = tid * 8;     // == ((r*8 + kks)*64 + l) * 8  (lane-linear)
        *reinterpret_cast<bf16x8*>(&Ah[off]) = hi;
        *reinterpret_cast<bf16x8*>(&Al[off]) = lo;
    }
    __syncthreads();

    // ---- main loop: per-kk B build (registers) + clean LDS A reads + MFMA ----
    f32x4 acc0 = (f32x4){0.f, 0.f, 0.f, 0.f};
    f32x4 acc1 = (f32x4){0.f, 0.f, 0.f, 0.f};
    float cpart = 0.0f;
    const size_t crow = (size_t)(n0 + ll) * Dn + lg * 4;   // col n0+ll, d-base lg*4

    float4 cv = *reinterpret_cast<const float4*>(cent + crow);
    float4 v4 = *reinterpret_cast<const float4*>(lvar + crow);

    #pragma unroll
    for (int kk = 0; kk < 8; ++kk) {
        float4 ncv, nv4;
        if (kk < 7) {   // prefetch next kk's cent/lvar (L2-resident)
            ncv = *reinterpret_cast<const float4*>(cent + crow + (kk + 1) * 16);
            nv4 = *reinterpret_cast<const float4*>(lvar + crow + (kk + 1) * 16);
        }
        const float a0 = __expf(-v4.x), a1 = __expf(-v4.y);
        const float a2 = __expf(-v4.z), a3 = __expf(-v4.w);
        const float f[8] = {a0, -2.0f * cv.x * a0, a1, -2.0f * cv.y * a1,
                            a2, -2.0f * cv.z * a2, a3, -2.0f * cv.w * a3};
        bf16x8 Bh, Bl;
        split8(f, Bh, Bl);
        cpart += cv.x * cv.x * a0 + cv.y * cv.y * a1 +
                 cv.z * cv.z * a2 + cv.w * cv.w * a3;

        const int ao = kk * 512 + l * 8;     // lane-linear ds_read_b128
        const bf16x8 a0h = *reinterpret_cast<const bf16x8*>(&Ah[ao]);
        const bf16x8 a0l = *reinterpret_cast<const bf16x8*>(&Al[ao]);
        const bf16x8 a1h = *reinterpret_cast<const bf16x8*>(&Ah[4096 + ao]);
        const bf16x8 a1l = *reinterpret_cast<const bf16x8*>(&Al[4096 + ao]);

        acc0 = __builtin_amdgcn_mfma_f32_16x16x32_bf16(a0h, Bh, acc0, 0, 0, 0);
        acc1 = __builtin_amdgcn_mfma_f32_16x16x32_bf16(a1h, Bh, acc1, 0, 0, 0);
        acc0 = __builtin_amdgcn_mfma_f32_16x16x32_bf16(a0h, Bl, acc0, 0, 0, 0);
        acc1 = __builtin_amdgcn_mfma_f32_16x16x32_bf16(a1h, Bl, acc1, 0, 0, 0);
        acc0 = __builtin_amdgcn_mfma_f32_16x16x32_bf16(a0l, Bh, acc0, 0, 0, 0);
        acc1 = __builtin_amdgcn_mfma_f32_16x16x32_bf16(a1l, Bh, acc1, 0, 0, 0);

        cv = ncv; v4 = nv4;
    }
    // c[k]: lane holds d-subsets {lg*4..} x {kk*16..}; sum over the 4 lg groups
    cpart += __shfl_xor(cpart, 16);
    cpart += __shfl_xor(cpart, 32);
    const float ck = cpart;          // c[n0+ll], matches C/D col = ll

    // ---- epilogue: dist = acc + ck; softmax over k (16 waves x 16 cols) ----
    float dv[2][4];
    #pragma unroll
    for (int r = 0; r < 4; ++r) { dv[0][r] = acc0[r] + ck; dv[1][r] = acc1[r] + ck; }

    #pragma unroll
    for (int mi = 0; mi < 2; ++mi)
        #pragma unroll
        for (int r = 0; r < 4; ++r) {
            float t = dv[mi][r];
            t = fminf(t, __shfl_xor(t, 1));
            t = fminf(t, __shfl_xor(t, 2));
            t = fminf(t, __shfl_xor(t, 4));
            t = fminf(t, __shfl_xor(t, 8));
            if (ll == 0) red[mi * 16 + lg * 4 + r][w] = t;
        }
    __syncthreads();

    float gm[2][4];
    #pragma unroll
    for (int mi = 0; mi < 2; ++mi)
        #pragma unroll
        for (int r = 0; r < 4; ++r) {
            const int row = mi * 16 + lg * 4 + r;
            const f32x4* rp = reinterpret_cast<const f32x4*>(&red[row][0]);
            f32x4 m4 = rp[0];
            #pragma unroll
            for (int q = 1; q < 4; ++q) {
                f32x4 v = rp[q];
                m4[0] = fminf(m4[0], v[0]); m4[1] = fminf(m4[1], v[1]);
                m4[2] = fminf(m4[2], v[2]); m4[3] = fminf(m4[3], v[3]);
            }
            gm[mi][r] = fminf(fminf(m4[0], m4[1]), fminf(m4[2], m4[3]));
        }
    __syncthreads();   // all red reads done before reuse

    float pv[2][4];
    #pragma unroll
    for (int mi = 0; mi < 2; ++mi)
        #pragma unroll
        for (int r = 0; r < 4; ++r) {
            const float p = __expf(-0.5f * (dv[mi][r] - gm[mi][r]));
            pv[mi][r] = p;
            float s = p;
            s += __shfl_xor(s, 1);
            s += __shfl_xor(s, 2);
            s += __shfl_xor(s, 4);
            s += __shfl_xor(s, 8);
            if (ll == 0) red[mi * 16 + lg * 4 + r][w] = s;
        }
    __syncthreads();

    #pragma unroll
    for (int mi = 0; mi < 2; ++mi)
        #pragma unroll
        for (int r = 0; r < 4; ++r) {
            const int row = mi * 16 + lg * 4 + r;
            const f32x4* rp = reinterpret_cast<const f32x4*>(&red[row][0]);
            f32x4 s4 = rp[0];
            #pragma unroll
            for (int q = 1; q < 4; ++q) {
                f32x4 v = rp[q];
                s4[0] += v[0]; s4[1] += v[1]; s4[2] += v[2]; s4[3] += v[3];
            }
            const float inv = 1.0f / ((s4[0] + s4[1]) + (s4[2] + s4[3]));
            out[(size_t)(b0 + row) * Kn + n0 + ll] = pv[mi][r] * inv;
        }
}

extern "C" void kernel_launch(void* const* d_in, const int* in_sizes, int n_in,
                              void* d_out, int out_size, void* d_ws, size_t ws_size,
                              hipStream_t stream) {
    const float* z      = (const float*)d_in[0];
    const float* cent   = (const float*)d_in[1];
    const float* logvar = (const float*)d_in[2];
    float* out = (float*)d_out;
    (void)in_sizes; (void)n_in; (void)out_size; (void)d_ws; (void)ws_size;

    hipLaunchKernelGGL(gmm_fused, dim3(Bn / 32), dim3(1024), 0, stream,
                       z, cent, logvar, out);
}